// Round 3
// baseline (3205.917 us; speedup 1.0000x reference)
//
#include <hip/hip_runtime.h>
#include <cstdint>
#include <cstddef>

#define D 256
#define NTOK 65536
#define KCODES 4096
#define Q_ELEMS (NTOK * D)   // 16777216

// ---------------- kernel 1a: codebook squared norms (f64 -> f32) ----------
// one 64-lane wave per row; block = 4 waves = 4 rows
__global__ __launch_bounds__(256) void ee_kernel(const float* __restrict__ cb,
                                                 float* __restrict__ se) {
  const int row = blockIdx.x * 4 + (threadIdx.x >> 6);
  const int lane = threadIdx.x & 63;
  const float4 v = reinterpret_cast<const float4*>(cb + (size_t)row * D)[lane];
  double s = (double)v.x * v.x + (double)v.y * v.y +
             (double)v.z * v.z + (double)v.w * v.w;
#pragma unroll
  for (int o = 32; o > 0; o >>= 1) s += __shfl_down(s, o, 64);
  if (lane == 0) se[row] = (float)s;
}

// ---------------- kernel 1b: token squared norms (f64 -> f32) -------------
__global__ __launch_bounds__(256) void xx_kernel(const float* __restrict__ x,
                                                 float* __restrict__ sx) {
  const int row = blockIdx.x * 4 + (threadIdx.x >> 6);
  const int lane = threadIdx.x & 63;
  const float4 v = reinterpret_cast<const float4*>(x + (size_t)row * D)[lane];
  double s = (double)v.x * v.x + (double)v.y * v.y +
             (double)v.z * v.z + (double)v.w * v.w;
#pragma unroll
  for (int o = 32; o > 0; o >>= 1) s += __shfl_down(s, o, 64);
  if (lane == 0) sx[row] = (float)s;
}

// ---------------- kernel 2: fused distance + argmin (np-f32 replica) ------
// Replicates numpy float32 semantics bit-for-bit:
//   dot(t,k)  = sequential f32 FMA chain over d=0..255 (BLAS microkernel order)
//   dist(t,k) = fl32( fl32(sx_t + se_k) - 2*dot )   (x2 exact; one rounding)
//   winner    = lowest index among equal f32 minima (np.argmin tie-break)
__global__ __launch_bounds__(256) void argmin_kernel(const float* __restrict__ x,
                                                     const float* __restrict__ cb,
                                                     const float* __restrict__ se,
                                                     const float* __restrict__ sx,
                                                     int* __restrict__ idx_out,
                                                     float* __restrict__ idxf_out) {
  // pad 68: row stride 272 B (16B-aligned for b128 reads), 68%32=4 breaks bank aliasing
  __shared__ float xs[D][68];
  __shared__ __attribute__((aligned(16))) float es[D][68];
  // reduction arrays aliased onto es (es dead after the ct loop; sync separates)
  float* red_val = reinterpret_cast<float*>(&es[0][0]);                   // [64][16]
  int* red_idx = reinterpret_cast<int*>((char*)&es[0][0] + 64 * 16 * 4);  // [64][16]

  const int tid = threadIdx.x;
  const int tg = tid & 15;   // token group: tokens tg*4 .. tg*4+3
  const int cg = tid >> 4;   // code group : codes  cg*4 .. cg*4+3 (within tile)
  const int tok0 = blockIdx.x * 64;

  // load x tile transposed: xs[d][t]
  for (int i = tid; i < 64 * (D / 4); i += 256) {
    const int t = i >> 6;
    const int dc = i & 63;
    const float4 v = reinterpret_cast<const float4*>(x + (size_t)(tok0 + t) * D)[dc];
    xs[dc * 4 + 0][t] = v.x;
    xs[dc * 4 + 1][t] = v.y;
    xs[dc * 4 + 2][t] = v.z;
    xs[dc * 4 + 3][t] = v.w;
  }

  float sxf[4];
#pragma unroll
  for (int i = 0; i < 4; ++i) sxf[i] = sx[tok0 + tg * 4 + i];

  float best_val[4];
  int best_idx[4];
#pragma unroll
  for (int i = 0; i < 4; ++i) { best_val[i] = 3.4e38f; best_idx[i] = 0; }

  for (int ct = 0; ct < KCODES / 64; ++ct) {
    __syncthreads();  // previous tile fully consumed (also covers x-tile load, iter 0)
    // load 64-code tile transposed: es[d][c]
    for (int i = tid; i < 64 * (D / 4); i += 256) {
      const int c = i >> 6;
      const int dc = i & 63;
      const float4 v =
          reinterpret_cast<const float4*>(cb + (size_t)(ct * 64 + c) * D)[dc];
      es[dc * 4 + 0][c] = v.x;
      es[dc * 4 + 1][c] = v.y;
      es[dc * 4 + 2][c] = v.z;
      es[dc * 4 + 3][c] = v.w;
    }
    __syncthreads();

    // sequential f32 FMA chain over the full D for each of 16 (t,k) pairs.
    // kk strictly ascending; single accumulator per pair -> BLAS chain order.
    float acc[4][4] = {};
#pragma unroll 4
    for (int kk = 0; kk < D; ++kk) {
      const float4 xv = *reinterpret_cast<const float4*>(&xs[kk][tg * 4]);
      const float4 ev = *reinterpret_cast<const float4*>(&es[kk][cg * 4]);
      const float xa[4] = {xv.x, xv.y, xv.z, xv.w};
      const float ea[4] = {ev.x, ev.y, ev.z, ev.w};
#pragma unroll
      for (int i = 0; i < 4; ++i)
#pragma unroll
        for (int j = 0; j < 4; ++j) acc[i][j] = fmaf(xa[i], ea[j], acc[i][j]);
    }

    // dist = fl(fl(sx+se) - 2*dot); j ascending => ascending code index;
    // strict '<' keeps the FIRST index on f32-equal minima (np.argmin).
#pragma unroll
    for (int j = 0; j < 4; ++j) {
      const int c = ct * 64 + cg * 4 + j;
      const float sef = se[c];
#pragma unroll
      for (int i = 0; i < 4; ++i) {
        const float r = sxf[i] + sef;          // rounds once (usually == sxf)
        const float s = r - 2.0f * acc[i][j];  // 2*acc exact; one more rounding
        if (s < best_val[i]) { best_val[i] = s; best_idx[i] = c; }
      }
    }
  }

  __syncthreads();
#pragma unroll
  for (int i = 0; i < 4; ++i) {
    red_val[(tg * 4 + i) * 16 + cg] = best_val[i];
    red_idx[(tg * 4 + i) * 16 + cg] = best_idx[i];
  }
  __syncthreads();
  // cross-thread lex-min (val, idx) -> global first-index tie-break
  if (tid < 64) {
    float bv = red_val[tid * 16 + 0];
    int bi = red_idx[tid * 16 + 0];
#pragma unroll
    for (int g = 1; g < 16; ++g) {
      const float v = red_val[tid * 16 + g];
      const int ix = red_idx[tid * 16 + g];
      if (v < bv || (v == bv && ix < bi)) { bv = v; bi = ix; }
    }
    idx_out[tok0 + tid] = bi;
    idxf_out[tok0 + tid] = (float)bi;  // harness reads whole d_out as f32
  }
}

// ---------------- kernel 3: gather, q_st, loss partials, histogram ----------------
// 16 tokens per block; 16 threads per token (16 dims each)
__global__ __launch_bounds__(256) void finalize_kernel(const float* __restrict__ x,
                                                       const float* __restrict__ cb,
                                                       const int* __restrict__ idx,
                                                       float* __restrict__ q_out,
                                                       unsigned int* __restrict__ counts,
                                                       double* __restrict__ partials) {
  __shared__ double tok_s[16];
  const int tid = threadIdx.x;
  const int lt = tid >> 4;
  const int ld = tid & 15;
  const int t = blockIdx.x * 16 + lt;
  const int id = idx[t];
  const float* xp = x + (size_t)t * D + ld * 16;
  const float* ep = cb + (size_t)id * D + ld * 16;
  float* qp = q_out + (size_t)t * D + ld * 16;
  float s = 0.0f;
#pragma unroll
  for (int c = 0; c < 4; ++c) {
    const float4 xv = reinterpret_cast<const float4*>(xp)[c];
    const float4 ev = reinterpret_cast<const float4*>(ep)[c];
    const float d0 = ev.x - xv.x, d1 = ev.y - xv.y;
    const float d2 = ev.z - xv.z, d3 = ev.w - xv.w;
    s = fmaf(d0, d0, s);
    s = fmaf(d1, d1, s);
    s = fmaf(d2, d2, s);
    s = fmaf(d3, d3, s);
    float4 qv;  // q_st = x + (q - x), computed exactly as the reference does
    qv.x = xv.x + d0;
    qv.y = xv.y + d1;
    qv.z = xv.z + d2;
    qv.w = xv.w + d3;
    reinterpret_cast<float4*>(qp)[c] = qv;
  }
#pragma unroll
  for (int o = 8; o > 0; o >>= 1) s += __shfl_down(s, o, 16);
  if (ld == 0) {
    atomicAdd(&counts[id], 1u);
    tok_s[lt] = (double)s;
  }
  __syncthreads();
  if (tid == 0) {
    double bs = 0.0;
    for (int i = 0; i < 16; ++i) bs += tok_s[i];
    partials[blockIdx.x] = bs;
  }
}

// ---------------- kernel 4: scalar reductions ----------------
__global__ __launch_bounds__(256) void final_kernel(const unsigned int* __restrict__ counts,
                                                    const double* __restrict__ partials,
                                                    float* __restrict__ loss_out,
                                                    float* __restrict__ perp_out) {
  __shared__ double sh[256];
  const int tid = threadIdx.x;
  double ls = 0.0;
  for (int i = tid; i < NTOK / 16; i += 256) ls += partials[i];
  sh[tid] = ls;
  __syncthreads();
#pragma unroll
  for (int o = 128; o > 0; o >>= 1) {
    if (tid < o) sh[tid] += sh[tid + o];
    __syncthreads();
  }
  if (tid == 0) {
    // per_token_loss = (1 + 0.25) * sum_d (q-x)^2 / D ; mean over NTOK tokens
    *loss_out = (float)(sh[0] * (1.25 / (256.0 * 65536.0)));
  }
  __syncthreads();
  double hs = 0.0;
  for (int i = tid; i < KCODES; i += 256) {
    const float p = (float)counts[i] / 65536.0f;
    hs += (double)(p * logf(p + 1e-10f));
  }
  sh[tid] = hs;
  __syncthreads();
#pragma unroll
  for (int o = 128; o > 0; o >>= 1) {
    if (tid < o) sh[tid] += sh[tid + o];
    __syncthreads();
  }
  if (tid == 0) *perp_out = expf((float)(-sh[0]));
}

extern "C" void kernel_launch(void* const* d_in, const int* in_sizes, int n_in,
                              void* d_out, int out_size, void* d_ws, size_t ws_size,
                              hipStream_t stream) {
  (void)in_sizes; (void)n_in; (void)out_size; (void)ws_size;
  const float* x = (const float*)d_in[0];
  const float* cb = (const float*)d_in[1];

  float* out = (float*)d_out;
  float* q_out = out;                                  // [0, 16777216)
  float* loss_out = out + (size_t)Q_ELEMS;             // [16777216]
  float* perp_out = out + (size_t)Q_ELEMS + 1;         // [16777217]
  float* idxf_out = out + (size_t)Q_ELEMS + 2;         // [16777218, +65536)

  // ws layout (bytes): se f32[4096] @0 ; counts u32[4096] @16K ;
  // partials f64[4096] @32K ; idx i32[65536] @64K ; sx f32[65536] @320K
  char* ws = (char*)d_ws;
  float* se = (float*)(ws + 0);
  unsigned int* counts = (unsigned int*)(ws + (16 << 10));
  double* partials = (double*)(ws + (32 << 10));
  int* idx_i = (int*)(ws + (64 << 10));
  float* sx = (float*)(ws + (320 << 10));

  hipMemsetAsync(counts, 0, KCODES * sizeof(unsigned int), stream);
  ee_kernel<<<KCODES / 4, 256, 0, stream>>>(cb, se);
  xx_kernel<<<NTOK / 4, 256, 0, stream>>>(x, sx);
  argmin_kernel<<<NTOK / 64, 256, 0, stream>>>(x, cb, se, sx, idx_i, idxf_out);
  finalize_kernel<<<NTOK / 16, 256, 0, stream>>>(x, cb, idx_i, q_out, counts, partials);
  final_kernel<<<1, 256, 0, stream>>>(counts, partials, loss_out, perp_out);
}

// Round 4
// 2000.169 us; speedup vs baseline: 1.6028x; 1.6028x over previous
//
#include <hip/hip_runtime.h>
#include <cstdint>
#include <cstddef>

#define D 256
#define NTOK 65536
#define KCODES 4096
#define Q_ELEMS (NTOK * D)   // 16777216

// ---------------- kernel 1a: codebook squared norms (f64 -> f32) ----------
__global__ __launch_bounds__(256) void ee_kernel(const float* __restrict__ cb,
                                                 float* __restrict__ se) {
  const int row = blockIdx.x * 4 + (threadIdx.x >> 6);
  const int lane = threadIdx.x & 63;
  const float4 v = reinterpret_cast<const float4*>(cb + (size_t)row * D)[lane];
  double s = (double)v.x * v.x + (double)v.y * v.y +
             (double)v.z * v.z + (double)v.w * v.w;
#pragma unroll
  for (int o = 32; o > 0; o >>= 1) s += __shfl_down(s, o, 64);
  if (lane == 0) se[row] = (float)s;
}

// ---------------- kernel 1b: token squared norms (f64 -> f32) -------------
__global__ __launch_bounds__(256) void xx_kernel(const float* __restrict__ x,
                                                 float* __restrict__ sx) {
  const int row = blockIdx.x * 4 + (threadIdx.x >> 6);
  const int lane = threadIdx.x & 63;
  const float4 v = reinterpret_cast<const float4*>(x + (size_t)row * D)[lane];
  double s = (double)v.x * v.x + (double)v.y * v.y +
             (double)v.z * v.z + (double)v.w * v.w;
#pragma unroll
  for (int o = 32; o > 0; o >>= 1) s += __shfl_down(s, o, 64);
  if (lane == 0) sx[row] = (float)s;
}

// ---------------- kernel 2: fused distance + argmin (np-f32 replica) ------
// 128 tokens x 128 codes per block, 256 threads, 8x8 register tile, BK=64.
// Tiles stored k-major in LDS (row = kk, 512 B rows => bank = column).
// Column rotation col' = (col + 8*(kk>>3)) & 127 makes BOTH the transposing
// staging writes and the broadcast compute reads <=2-way bank aliasing (free).
// f32 semantics identical to the round-3 passing kernel:
//   dot = sequential fmaf chain d=0..255; dist = fl(fl(sx+se) - 2*dot);
//   argmin with strict '<' + lowest-index tie-break.
__global__ __launch_bounds__(256) void argmin_kernel(const float* __restrict__ x,
                                                     const float* __restrict__ cb,
                                                     const float* __restrict__ se,
                                                     const float* __restrict__ sx,
                                                     int* __restrict__ idx_out,
                                                     float* __restrict__ idxf_out) {
  __shared__ __attribute__((aligned(16))) float xs[64 * 128];  // 32 KB
  __shared__ __attribute__((aligned(16))) float es[64 * 128];  // 32 KB

  const int tid = threadIdx.x;
  const int lane = tid & 63;
  const int w = tid >> 6;
  const int wt = w & 1;        // wave token-half
  const int wc = w >> 1;       // wave code-half
  const int tgl = lane & 7;    // token group in lane
  const int cgl = lane >> 3;   // code group in lane
  const int t0 = wt * 64 + tgl * 8;  // local token base (8 tokens)
  const int c0 = wc * 64 + cgl * 8;  // local code base (8 codes)
  const int tok0 = blockIdx.x * 128;

  float sxf[8];
#pragma unroll
  for (int i = 0; i < 8; ++i) sxf[i] = sx[tok0 + t0 + i];

  float bv[8];
  int bi[8];
#pragma unroll
  for (int i = 0; i < 8; ++i) { bv[i] = 3.4e38f; bi[i] = 0; }

  for (int ct = 0; ct < KCODES / 128; ++ct) {
    float acc[8][8] = {};
    for (int kt = 0; kt < 4; ++kt) {
      __syncthreads();  // previous tile fully consumed
      // ---- stage x[128 tok][64 dims] and cb[128 codes][64 dims], transposed
      // thread p-iter handles (t = idx>>4, c = idx&15): global reads are 4
      // tokens x 256 B contiguous per wave (coalesced); LDS writes land in
      // column (t + 8*(c>>1)) & 127 of rows c*4+j  => 2 lanes/bank.
      {
        const float* xsrc = x + (size_t)tok0 * D + kt * 64;
        const float* esrc = cb + (size_t)(ct * 128) * D + kt * 64;
#pragma unroll
        for (int p = 0; p < 8; ++p) {
          const int idx = p * 256 + tid;
          const int t = idx >> 4;
          const int c = idx & 15;
          const int colp = (t + 8 * (c >> 1)) & 127;
          const float4 xv = *reinterpret_cast<const float4*>(xsrc + (size_t)t * D + c * 4);
          float* xd = &xs[(c * 4) * 128 + colp];
          xd[0] = xv.x; xd[128] = xv.y; xd[256] = xv.z; xd[384] = xv.w;
          const float4 ev = *reinterpret_cast<const float4*>(esrc + (size_t)t * D + c * 4);
          float* ed = &es[(c * 4) * 128 + colp];
          ed[0] = ev.x; ed[128] = ev.y; ed[256] = ev.z; ed[384] = ev.w;
        }
      }
      __syncthreads();
      // ---- compute 64 kk steps; kk = kg*8 + k2 strictly ascending
      for (int kg = 0; kg < 8; ++kg) {
        const float* xb = &xs[(kg * 8) * 128 + ((t0 + 8 * kg) & 127)];
        const float* eb = &es[(kg * 8) * 128 + ((c0 + 8 * kg) & 127)];
#pragma unroll
        for (int k2 = 0; k2 < 8; ++k2) {
          const float4 xv0 = *reinterpret_cast<const float4*>(xb + k2 * 128);
          const float4 xv1 = *reinterpret_cast<const float4*>(xb + k2 * 128 + 4);
          const float4 ev0 = *reinterpret_cast<const float4*>(eb + k2 * 128);
          const float4 ev1 = *reinterpret_cast<const float4*>(eb + k2 * 128 + 4);
          const float xa[8] = {xv0.x, xv0.y, xv0.z, xv0.w,
                               xv1.x, xv1.y, xv1.z, xv1.w};
          const float ea[8] = {ev0.x, ev0.y, ev0.z, ev0.w,
                               ev1.x, ev1.y, ev1.z, ev1.w};
#pragma unroll
          for (int i = 0; i < 8; ++i)
#pragma unroll
            for (int j = 0; j < 8; ++j)
              acc[i][j] = fmaf(xa[i], ea[j], acc[i][j]);
        }
      }
    }
    // ---- score this 128-code tile; j ascending => code index ascending
#pragma unroll
    for (int j = 0; j < 8; ++j) {
      const int cidx = ct * 128 + c0 + j;
      const float sef = se[cidx];
#pragma unroll
      for (int i = 0; i < 8; ++i) {
        const float r = sxf[i] + sef;          // one rounding
        const float s = r - 2.0f * acc[i][j];  // 2*acc exact; one rounding
        if (s < bv[i]) { bv[i] = s; bi[i] = cidx; }
      }
    }
  }

  // ---- cross-thread reduction: token t is held by 16 threads (wc, cgl).
  __syncthreads();
  float* red_val = xs;                                   // [128][17] overlay
  int* red_idx = reinterpret_cast<int*>(xs + 128 * 17);  // [128][17]
  const int g = wc * 8 + cgl;
#pragma unroll
  for (int i = 0; i < 8; ++i) {
    red_val[(t0 + i) * 17 + g] = bv[i];
    red_idx[(t0 + i) * 17 + g] = bi[i];
  }
  __syncthreads();
  if (tid < 128) {
    float v = red_val[tid * 17 + 0];
    int ix = red_idx[tid * 17 + 0];
#pragma unroll
    for (int gg = 1; gg < 16; ++gg) {
      const float vv = red_val[tid * 17 + gg];
      const int ii = red_idx[tid * 17 + gg];
      if (vv < v || (vv == v && ii < ix)) { v = vv; ix = ii; }
    }
    idx_out[tok0 + tid] = ix;
    idxf_out[tok0 + tid] = (float)ix;  // harness reads whole d_out as f32
  }
}

// ---------------- kernel 3: gather, q_st, loss partials, histogram --------
__global__ __launch_bounds__(256) void finalize_kernel(const float* __restrict__ x,
                                                       const float* __restrict__ cb,
                                                       const int* __restrict__ idx,
                                                       float* __restrict__ q_out,
                                                       unsigned int* __restrict__ counts,
                                                       double* __restrict__ partials) {
  __shared__ double tok_s[16];
  const int tid = threadIdx.x;
  const int lt = tid >> 4;
  const int ld = tid & 15;
  const int t = blockIdx.x * 16 + lt;
  const int id = idx[t];
  const float* xp = x + (size_t)t * D + ld * 16;
  const float* ep = cb + (size_t)id * D + ld * 16;
  float* qp = q_out + (size_t)t * D + ld * 16;
  float s = 0.0f;
#pragma unroll
  for (int c = 0; c < 4; ++c) {
    const float4 xv = reinterpret_cast<const float4*>(xp)[c];
    const float4 ev = reinterpret_cast<const float4*>(ep)[c];
    const float d0 = ev.x - xv.x, d1 = ev.y - xv.y;
    const float d2 = ev.z - xv.z, d3 = ev.w - xv.w;
    s = fmaf(d0, d0, s);
    s = fmaf(d1, d1, s);
    s = fmaf(d2, d2, s);
    s = fmaf(d3, d3, s);
    float4 qv;  // q_st = x + (q - x), as the reference computes it
    qv.x = xv.x + d0;
    qv.y = xv.y + d1;
    qv.z = xv.z + d2;
    qv.w = xv.w + d3;
    reinterpret_cast<float4*>(qp)[c] = qv;
  }
#pragma unroll
  for (int o = 8; o > 0; o >>= 1) s += __shfl_down(s, o, 16);
  if (ld == 0) {
    atomicAdd(&counts[id], 1u);
    tok_s[lt] = (double)s;
  }
  __syncthreads();
  if (tid == 0) {
    double bs = 0.0;
    for (int i = 0; i < 16; ++i) bs += tok_s[i];
    partials[blockIdx.x] = bs;
  }
}

// ---------------- kernel 4: scalar reductions ----------------
__global__ __launch_bounds__(256) void final_kernel(const unsigned int* __restrict__ counts,
                                                    const double* __restrict__ partials,
                                                    float* __restrict__ loss_out,
                                                    float* __restrict__ perp_out) {
  __shared__ double sh[256];
  const int tid = threadIdx.x;
  double ls = 0.0;
  for (int i = tid; i < NTOK / 16; i += 256) ls += partials[i];
  sh[tid] = ls;
  __syncthreads();
#pragma unroll
  for (int o = 128; o > 0; o >>= 1) {
    if (tid < o) sh[tid] += sh[tid + o];
    __syncthreads();
  }
  if (tid == 0) {
    *loss_out = (float)(sh[0] * (1.25 / (256.0 * 65536.0)));
  }
  __syncthreads();
  double hs = 0.0;
  for (int i = tid; i < KCODES; i += 256) {
    const float p = (float)counts[i] / 65536.0f;
    hs += (double)(p * logf(p + 1e-10f));
  }
  sh[tid] = hs;
  __syncthreads();
#pragma unroll
  for (int o = 128; o > 0; o >>= 1) {
    if (tid < o) sh[tid] += sh[tid + o];
    __syncthreads();
  }
  if (tid == 0) *perp_out = expf((float)(-sh[0]));
}

extern "C" void kernel_launch(void* const* d_in, const int* in_sizes, int n_in,
                              void* d_out, int out_size, void* d_ws, size_t ws_size,
                              hipStream_t stream) {
  (void)in_sizes; (void)n_in; (void)out_size; (void)ws_size;
  const float* x = (const float*)d_in[0];
  const float* cb = (const float*)d_in[1];

  float* out = (float*)d_out;
  float* q_out = out;                                  // [0, 16777216)
  float* loss_out = out + (size_t)Q_ELEMS;             // [16777216]
  float* perp_out = out + (size_t)Q_ELEMS + 1;         // [16777217]
  float* idxf_out = out + (size_t)Q_ELEMS + 2;         // [16777218, +65536)

  // ws layout (bytes): se f32[4096] @0 ; counts u32[4096] @16K ;
  // partials f64[4096] @32K ; idx i32[65536] @64K ; sx f32[65536] @320K
  char* ws = (char*)d_ws;
  float* se = (float*)(ws + 0);
  unsigned int* counts = (unsigned int*)(ws + (16 << 10));
  double* partials = (double*)(ws + (32 << 10));
  int* idx_i = (int*)(ws + (64 << 10));
  float* sx = (float*)(ws + (320 << 10));

  hipMemsetAsync(counts, 0, KCODES * sizeof(unsigned int), stream);
  ee_kernel<<<KCODES / 4, 256, 0, stream>>>(cb, se);
  xx_kernel<<<NTOK / 4, 256, 0, stream>>>(x, sx);
  argmin_kernel<<<NTOK / 128, 256, 0, stream>>>(x, cb, se, sx, idx_i, idxf_out);
  finalize_kernel<<<NTOK / 16, 256, 0, stream>>>(x, cb, idx_i, q_out, counts, partials);
  final_kernel<<<1, 256, 0, stream>>>(counts, partials, loss_out, perp_out);
}

// Round 5
// 1921.432 us; speedup vs baseline: 1.6685x; 1.0410x over previous
//
#include <hip/hip_runtime.h>
#include <cstdint>
#include <cstddef>

#define D 256
#define NTOK 65536
#define KCODES 4096
#define Q_ELEMS (NTOK * D)   // 16777216

// async global->LDS DMA, 16B per lane, dest = wave-uniform base + lane*16
__device__ __forceinline__ void gload_lds16(const float* g, float* l) {
  __builtin_amdgcn_global_load_lds(
      (const __attribute__((address_space(1))) void*)(g),
      (__attribute__((address_space(3))) void*)(l), 16, 0, 0);
}

// ---------------- kernel 1a: codebook squared norms (f64 -> f32) ----------
__global__ __launch_bounds__(256) void ee_kernel(const float* __restrict__ cb,
                                                 float* __restrict__ se) {
  const int row = blockIdx.x * 4 + (threadIdx.x >> 6);
  const int lane = threadIdx.x & 63;
  const float4 v = reinterpret_cast<const float4*>(cb + (size_t)row * D)[lane];
  double s = (double)v.x * v.x + (double)v.y * v.y +
             (double)v.z * v.z + (double)v.w * v.w;
#pragma unroll
  for (int o = 32; o > 0; o >>= 1) s += __shfl_down(s, o, 64);
  if (lane == 0) se[row] = (float)s;
}

// ---------------- kernel 1b: token squared norms (f64 -> f32) -------------
__global__ __launch_bounds__(256) void xx_kernel(const float* __restrict__ x,
                                                 float* __restrict__ sx) {
  const int row = blockIdx.x * 4 + (threadIdx.x >> 6);
  const int lane = threadIdx.x & 63;
  const float4 v = reinterpret_cast<const float4*>(x + (size_t)row * D)[lane];
  double s = (double)v.x * v.x + (double)v.y * v.y +
             (double)v.z * v.z + (double)v.w * v.w;
#pragma unroll
  for (int o = 32; o > 0; o >>= 1) s += __shfl_down(s, o, 64);
  if (lane == 0) sx[row] = (float)s;
}

// ---------------- kernel 1c: 64x64-tile transpose src[N][256]->dst[256][N] -
__global__ __launch_bounds__(256) void transpose_kernel(const float* __restrict__ src,
                                                        float* __restrict__ dst,
                                                        int N) {
  __shared__ float ls[64][65];
  const int tid = threadIdx.x;
  const int t0b = blockIdx.x * 64;
  const int d0b = blockIdx.y * 64;
#pragma unroll
  for (int i = 0; i < 4; ++i) {
    const int t = i * 16 + (tid >> 4);
    const float4 v = *reinterpret_cast<const float4*>(
        src + (size_t)(t0b + t) * D + d0b + (tid & 15) * 4);
    ls[t][(tid & 15) * 4 + 0] = v.x;
    ls[t][(tid & 15) * 4 + 1] = v.y;
    ls[t][(tid & 15) * 4 + 2] = v.z;
    ls[t][(tid & 15) * 4 + 3] = v.w;
  }
  __syncthreads();
#pragma unroll
  for (int i = 0; i < 4; ++i) {
    const int d = i * 16 + (tid >> 4);
    const int t4 = (tid & 15) * 4;
    float4 w;
    w.x = ls[t4 + 0][d];
    w.y = ls[t4 + 1][d];
    w.z = ls[t4 + 2][d];
    w.w = ls[t4 + 3][d];
    *reinterpret_cast<float4*>(dst + (size_t)(d0b + d) * N + t0b + t4) = w;
  }
}

// ---------------- kernel 2: fused distance + argmin (DMA pipeline) --------
// 128 tokens x 128 codes per block, 256 threads, 8x8 register tile, BK=64.
// Operands pre-transposed in global (xT[256][65536], cbT[256][4096]) so each
// k-major LDS tile is a linear 2D copy staged via global_load_lds (no VALU,
// no ds_write). Double-buffered: next tile's DMA issued before computing the
// current one; __syncthreads' vmcnt drain is then free (loads landed under
// ~8200cy of FMAs). Column involution pi(c) = c ^ ((c&32)>>3) applied on the
// GLOBAL source (LDS dest stays DMA-linear; read uses the same pi) spreads
// ds_read_b128 banks to 8 distinct groups -> conflict-free.
// f32 semantics identical to the round-3/4 passing kernels:
//   dot = sequential fmaf chain d=0..255 (kt-major, rows ascending);
//   dist = fl(fl(sx+se) - 2*dot); argmin strict '<' + lowest-index tie-break.
__global__ __launch_bounds__(256) void argmin_dma_kernel(const float* __restrict__ xT,
                                                         const float* __restrict__ cbT,
                                                         const float* __restrict__ se,
                                                         const float* __restrict__ sx,
                                                         int* __restrict__ idx_out,
                                                         float* __restrict__ idxf_out) {
  // [0]=xbuf0 [1]=xbuf1 [2]=ebuf0 [3]=ebuf1, each 64 rows x 128 cols (32 KB)
  __shared__ __attribute__((aligned(16))) float smem[4 * 64 * 128];  // 128 KB

  const int tid = threadIdx.x;
  const int lane = tid & 63;
  const int w = tid >> 6;
  const int wt = w & 1;        // wave token-half
  const int wc = w >> 1;       // wave code-half
  const int tgl = lane & 7;
  const int cgl = lane >> 3;
  const int t0 = wt * 64 + tgl * 8;  // 8 tokens per thread
  const int c0 = wc * 64 + cgl * 8;  // 8 codes per thread
  const int tok0 = blockIdx.x * 128;

  // swizzled read columns (pi involution; handles the bit5-conditioned bit2 flip)
  const int st = (t0 & 32) >> 3;
  const int xc0 = t0 ^ st;           // cols of tokens t0..t0+3
  const int xc1 = (t0 + 4) ^ st;     // cols of tokens t0+4..t0+7
  const int sc_ = (c0 & 32) >> 3;
  const int ec0 = c0 ^ sc_;
  const int ec1 = (c0 + 4) ^ sc_;

  // per-lane DMA source column: LDS col block (lane&31)*4 holds global
  // tokens/codes pi(col)..pi(col)+3
  const int dcol = (lane & 31) * 4;
  const int scp = dcol ^ ((dcol & 32) >> 3);
  const int srow = lane >> 5;

  // stage 64 k-rows into buffer `dst`: wave w covers rows w*16..w*16+15
  auto STAGE = [&](int dst, int kbase, int cb0) {
#pragma unroll
    for (int i = 0; i < 8; ++i) {
      const int r = (w << 4) + (i << 1);
      gload_lds16(xT + (size_t)(kbase + r + srow) * NTOK + tok0 + scp,
                  &smem[dst * 8192 + r * 128]);
      gload_lds16(cbT + (size_t)(kbase + r + srow) * KCODES + cb0 + scp,
                  &smem[(2 + dst) * 8192 + r * 128]);
    }
  };

  float sxf[8];
#pragma unroll
  for (int i = 0; i < 8; ++i) sxf[i] = sx[tok0 + t0 + i];

  float bv[8];
  int bi[8];
#pragma unroll
  for (int i = 0; i < 8; ++i) { bv[i] = 3.4e38f; bi[i] = 0; }

  float acc[8][8];
  int cur = 0;
  STAGE(0, 0, 0);
  __syncthreads();  // drains vmcnt(0): first tile resident

  for (int ctkt = 0; ctkt < 128; ++ctkt) {
    const int ct = ctkt >> 2;
    const int kt = ctkt & 3;
    // issue next tile's DMA into the other buffer (safe: everyone finished
    // reading it at the previous iteration's barrier)
    if (ctkt + 1 < 128) {
      const int n = ctkt + 1;
      STAGE(cur ^ 1, (n & 3) * 64, (n >> 2) * 128);
    }
    if (kt == 0) {
#pragma unroll
      for (int i = 0; i < 8; ++i)
#pragma unroll
        for (int j = 0; j < 8; ++j) acc[i][j] = 0.0f;
    }
    // compute: rows kbase..kbase+63 in ascending kk order (f32 chain order)
    {
      const float* xb = &smem[cur * 8192];
      const float* eb = &smem[(2 + cur) * 8192];
      for (int kg = 0; kg < 8; ++kg) {
#pragma unroll
        for (int k2 = 0; k2 < 8; ++k2) {
          const int ro = (kg * 8 + k2) * 128;
          const float4 xv0 = *reinterpret_cast<const float4*>(xb + ro + xc0);
          const float4 xv1 = *reinterpret_cast<const float4*>(xb + ro + xc1);
          const float4 ev0 = *reinterpret_cast<const float4*>(eb + ro + ec0);
          const float4 ev1 = *reinterpret_cast<const float4*>(eb + ro + ec1);
          const float xa[8] = {xv0.x, xv0.y, xv0.z, xv0.w,
                               xv1.x, xv1.y, xv1.z, xv1.w};
          const float ea[8] = {ev0.x, ev0.y, ev0.z, ev0.w,
                               ev1.x, ev1.y, ev1.z, ev1.w};
#pragma unroll
          for (int i = 0; i < 8; ++i)
#pragma unroll
            for (int j = 0; j < 8; ++j)
              acc[i][j] = fmaf(xa[i], ea[j], acc[i][j]);
        }
      }
    }
    if (kt == 3) {
      // score the finished 128-code tile; j ascending => code idx ascending
#pragma unroll
      for (int j = 0; j < 8; ++j) {
        const int cidx = ct * 128 + c0 + j;
        const float sef = se[cidx];
#pragma unroll
        for (int i = 0; i < 8; ++i) {
          const float r = sxf[i] + sef;          // one rounding
          const float s = r - 2.0f * acc[i][j];  // 2*acc exact; one rounding
          if (s < bv[i]) { bv[i] = s; bi[i] = cidx; }
        }
      }
    }
    __syncthreads();  // vmcnt(0)+lgkmcnt(0)+barrier: next tile resident
    cur ^= 1;
  }

  // ---- cross-thread reduction (overlay on smem; barrier above separates)
  float* red_val = smem;                                    // [128][17]
  int* red_idx = reinterpret_cast<int*>(smem + 128 * 17);   // [128][17]
  const int g = wc * 8 + cgl;
#pragma unroll
  for (int i = 0; i < 8; ++i) {
    red_val[(t0 + i) * 17 + g] = bv[i];
    red_idx[(t0 + i) * 17 + g] = bi[i];
  }
  __syncthreads();
  if (tid < 128) {
    float v = red_val[tid * 17 + 0];
    int ix = red_idx[tid * 17 + 0];
#pragma unroll
    for (int gg = 1; gg < 16; ++gg) {
      const float vv = red_val[tid * 17 + gg];
      const int ii = red_idx[tid * 17 + gg];
      if (vv < v || (vv == v && ii < ix)) { v = vv; ix = ii; }
    }
    idx_out[tok0 + tid] = ix;
    idxf_out[tok0 + tid] = (float)ix;
  }
}

// ---------------- kernel 2-fallback: round-4 argmin (if ws too small) -----
__global__ __launch_bounds__(256) void argmin_fb_kernel(const float* __restrict__ x,
                                                        const float* __restrict__ cb,
                                                        const float* __restrict__ se,
                                                        const float* __restrict__ sx,
                                                        int* __restrict__ idx_out,
                                                        float* __restrict__ idxf_out) {
  __shared__ __attribute__((aligned(16))) float xs[64 * 128];
  __shared__ __attribute__((aligned(16))) float es[64 * 128];
  const int tid = threadIdx.x;
  const int lane = tid & 63;
  const int w = tid >> 6;
  const int wt = w & 1;
  const int wc = w >> 1;
  const int tgl = lane & 7;
  const int cgl = lane >> 3;
  const int t0 = wt * 64 + tgl * 8;
  const int c0 = wc * 64 + cgl * 8;
  const int tok0 = blockIdx.x * 128;
  float sxf[8];
#pragma unroll
  for (int i = 0; i < 8; ++i) sxf[i] = sx[tok0 + t0 + i];
  float bv[8];
  int bi[8];
#pragma unroll
  for (int i = 0; i < 8; ++i) { bv[i] = 3.4e38f; bi[i] = 0; }
  for (int ct = 0; ct < KCODES / 128; ++ct) {
    float acc[8][8] = {};
    for (int kt = 0; kt < 4; ++kt) {
      __syncthreads();
      {
        const float* xsrc = x + (size_t)tok0 * D + kt * 64;
        const float* esrc = cb + (size_t)(ct * 128) * D + kt * 64;
#pragma unroll
        for (int p = 0; p < 8; ++p) {
          const int idx = p * 256 + tid;
          const int t = idx >> 4;
          const int c = idx & 15;
          const int colp = (t + 8 * (c >> 1)) & 127;
          const float4 xv = *reinterpret_cast<const float4*>(xsrc + (size_t)t * D + c * 4);
          float* xd = &xs[(c * 4) * 128 + colp];
          xd[0] = xv.x; xd[128] = xv.y; xd[256] = xv.z; xd[384] = xv.w;
          const float4 ev = *reinterpret_cast<const float4*>(esrc + (size_t)t * D + c * 4);
          float* ed = &es[(c * 4) * 128 + colp];
          ed[0] = ev.x; ed[128] = ev.y; ed[256] = ev.z; ed[384] = ev.w;
        }
      }
      __syncthreads();
      for (int kg = 0; kg < 8; ++kg) {
        const float* xb = &xs[(kg * 8) * 128 + ((t0 + 8 * kg) & 127)];
        const float* eb = &es[(kg * 8) * 128 + ((c0 + 8 * kg) & 127)];
#pragma unroll
        for (int k2 = 0; k2 < 8; ++k2) {
          const float4 xv0 = *reinterpret_cast<const float4*>(xb + k2 * 128);
          const float4 xv1 = *reinterpret_cast<const float4*>(xb + k2 * 128 + 4);
          const float4 ev0 = *reinterpret_cast<const float4*>(eb + k2 * 128);
          const float4 ev1 = *reinterpret_cast<const float4*>(eb + k2 * 128 + 4);
          const float xa[8] = {xv0.x, xv0.y, xv0.z, xv0.w, xv1.x, xv1.y, xv1.z, xv1.w};
          const float ea[8] = {ev0.x, ev0.y, ev0.z, ev0.w, ev1.x, ev1.y, ev1.z, ev1.w};
#pragma unroll
          for (int i = 0; i < 8; ++i)
#pragma unroll
            for (int j = 0; j < 8; ++j) acc[i][j] = fmaf(xa[i], ea[j], acc[i][j]);
        }
      }
    }
#pragma unroll
    for (int j = 0; j < 8; ++j) {
      const int cidx = ct * 128 + c0 + j;
      const float sef = se[cidx];
#pragma unroll
      for (int i = 0; i < 8; ++i) {
        const float r = sxf[i] + sef;
        const float s = r - 2.0f * acc[i][j];
        if (s < bv[i]) { bv[i] = s; bi[i] = cidx; }
      }
    }
  }
  __syncthreads();
  float* red_val = xs;
  int* red_idx = reinterpret_cast<int*>(xs + 128 * 17);
  const int g = wc * 8 + cgl;
#pragma unroll
  for (int i = 0; i < 8; ++i) {
    red_val[(t0 + i) * 17 + g] = bv[i];
    red_idx[(t0 + i) * 17 + g] = bi[i];
  }
  __syncthreads();
  if (tid < 128) {
    float v = red_val[tid * 17 + 0];
    int ix = red_idx[tid * 17 + 0];
#pragma unroll
    for (int gg = 1; gg < 16; ++gg) {
      const float vv = red_val[tid * 17 + gg];
      const int ii = red_idx[tid * 17 + gg];
      if (vv < v || (vv == v && ii < ix)) { v = vv; ix = ii; }
    }
    idx_out[tok0 + tid] = ix;
    idxf_out[tok0 + tid] = (float)ix;
  }
}

// ---------------- kernel 3: gather, q_st, loss partials, histogram --------
__global__ __launch_bounds__(256) void finalize_kernel(const float* __restrict__ x,
                                                       const float* __restrict__ cb,
                                                       const int* __restrict__ idx,
                                                       float* __restrict__ q_out,
                                                       unsigned int* __restrict__ counts,
                                                       double* __restrict__ partials) {
  __shared__ double tok_s[16];
  const int tid = threadIdx.x;
  const int lt = tid >> 4;
  const int ld = tid & 15;
  const int t = blockIdx.x * 16 + lt;
  const int id = idx[t];
  const float* xp = x + (size_t)t * D + ld * 16;
  const float* ep = cb + (size_t)id * D + ld * 16;
  float* qp = q_out + (size_t)t * D + ld * 16;
  float s = 0.0f;
#pragma unroll
  for (int c = 0; c < 4; ++c) {
    const float4 xv = reinterpret_cast<const float4*>(xp)[c];
    const float4 ev = reinterpret_cast<const float4*>(ep)[c];
    const float d0 = ev.x - xv.x, d1 = ev.y - xv.y;
    const float d2 = ev.z - xv.z, d3 = ev.w - xv.w;
    s = fmaf(d0, d0, s);
    s = fmaf(d1, d1, s);
    s = fmaf(d2, d2, s);
    s = fmaf(d3, d3, s);
    float4 qv;  // q_st = x + (q - x), as the reference computes it
    qv.x = xv.x + d0;
    qv.y = xv.y + d1;
    qv.z = xv.z + d2;
    qv.w = xv.w + d3;
    reinterpret_cast<float4*>(qp)[c] = qv;
  }
#pragma unroll
  for (int o = 8; o > 0; o >>= 1) s += __shfl_down(s, o, 16);
  if (ld == 0) {
    atomicAdd(&counts[id], 1u);
    tok_s[lt] = (double)s;
  }
  __syncthreads();
  if (tid == 0) {
    double bs = 0.0;
    for (int i = 0; i < 16; ++i) bs += tok_s[i];
    partials[blockIdx.x] = bs;
  }
}

// ---------------- kernel 4: scalar reductions ----------------
__global__ __launch_bounds__(256) void final_kernel(const unsigned int* __restrict__ counts,
                                                    const double* __restrict__ partials,
                                                    float* __restrict__ loss_out,
                                                    float* __restrict__ perp_out) {
  __shared__ double sh[256];
  const int tid = threadIdx.x;
  double ls = 0.0;
  for (int i = tid; i < NTOK / 16; i += 256) ls += partials[i];
  sh[tid] = ls;
  __syncthreads();
#pragma unroll
  for (int o = 128; o > 0; o >>= 1) {
    if (tid < o) sh[tid] += sh[tid + o];
    __syncthreads();
  }
  if (tid == 0) {
    *loss_out = (float)(sh[0] * (1.25 / (256.0 * 65536.0)));
  }
  __syncthreads();
  double hs = 0.0;
  for (int i = tid; i < KCODES; i += 256) {
    const float p = (float)counts[i] / 65536.0f;
    hs += (double)(p * logf(p + 1e-10f));
  }
  sh[tid] = hs;
  __syncthreads();
#pragma unroll
  for (int o = 128; o > 0; o >>= 1) {
    if (tid < o) sh[tid] += sh[tid + o];
    __syncthreads();
  }
  if (tid == 0) *perp_out = expf((float)(-sh[0]));
}

extern "C" void kernel_launch(void* const* d_in, const int* in_sizes, int n_in,
                              void* d_out, int out_size, void* d_ws, size_t ws_size,
                              hipStream_t stream) {
  (void)in_sizes; (void)n_in; (void)out_size;
  const float* x = (const float*)d_in[0];
  const float* cb = (const float*)d_in[1];

  float* out = (float*)d_out;
  float* q_out = out;                                  // [0, 16777216)
  float* loss_out = out + (size_t)Q_ELEMS;             // [16777216]
  float* perp_out = out + (size_t)Q_ELEMS + 1;         // [16777217]
  float* idxf_out = out + (size_t)Q_ELEMS + 2;         // [16777218, +65536)

  // ws layout (bytes): se f32[4096] @0 ; counts u32[4096] @16K ;
  // partials f64[4096] @32K ; idx i32[65536] @64K ; sx f32[65536] @320K ;
  // cbT f32[256][4096] @1M (4MB) ; xT f32[256][65536] @8M (64MB)
  char* ws = (char*)d_ws;
  float* se = (float*)(ws + 0);
  unsigned int* counts = (unsigned int*)(ws + (16 << 10));
  double* partials = (double*)(ws + (32 << 10));
  int* idx_i = (int*)(ws + (64 << 10));
  float* sx = (float*)(ws + (320 << 10));
  float* cbT = (float*)(ws + (1 << 20));
  float* xT = (float*)(ws + (8 << 20));

  hipMemsetAsync(counts, 0, KCODES * sizeof(unsigned int), stream);
  ee_kernel<<<KCODES / 4, 256, 0, stream>>>(cb, se);
  xx_kernel<<<NTOK / 4, 256, 0, stream>>>(x, sx);

  if (ws_size >= (size_t)72 * 1024 * 1024) {
    transpose_kernel<<<dim3(NTOK / 64, 4), 256, 0, stream>>>(x, xT, NTOK);
    transpose_kernel<<<dim3(KCODES / 64, 4), 256, 0, stream>>>(cb, cbT, KCODES);
    argmin_dma_kernel<<<NTOK / 128, 256, 0, stream>>>(xT, cbT, se, sx, idx_i, idxf_out);
  } else {
    argmin_fb_kernel<<<NTOK / 128, 256, 0, stream>>>(x, cb, se, sx, idx_i, idxf_out);
  }
  finalize_kernel<<<NTOK / 16, 256, 0, stream>>>(x, cb, idx_i, q_out, counts, partials);
  final_kernel<<<1, 256, 0, stream>>>(counts, partials, loss_out, perp_out);
}

// Round 6
// 613.021 us; speedup vs baseline: 5.2297x; 3.1344x over previous
//
#include <hip/hip_runtime.h>
#include <hip/hip_bf16.h>
#include <cstdint>
#include <cstddef>

#define D 256
#define NTOK 65536
#define KCODES 4096
#define Q_ELEMS (NTOK * D)   // 16777216
#define DELTA 1.5e-4f

typedef short bf16x8 __attribute__((ext_vector_type(8)));
typedef float f32x4 __attribute__((ext_vector_type(4)));
typedef unsigned short ushort8 __attribute__((ext_vector_type(8)));

__device__ __forceinline__ void gload_lds16(const float* g, float* l) {
  __builtin_amdgcn_global_load_lds(
      (const __attribute__((address_space(1))) void*)(g),
      (__attribute__((address_space(3))) void*)(l), 16, 0, 0);
}
__device__ __forceinline__ unsigned short f2bf(float f) {
  __hip_bfloat16 h = __float2bfloat16(f);
  unsigned short u;
  __builtin_memcpy(&u, &h, 2);
  return u;
}
__device__ __forceinline__ float bf2f(unsigned short u) {
  __hip_bfloat16 h;
  __builtin_memcpy(&h, &u, 2);
  return __bfloat162float(h);
}

// ---------------- kernel 1a: codebook squared norms (f64 -> f32) ----------
__global__ __launch_bounds__(256) void ee_kernel(const float* __restrict__ cb,
                                                 float* __restrict__ se) {
  const int row = blockIdx.x * 4 + (threadIdx.x >> 6);
  const int lane = threadIdx.x & 63;
  const float4 v = reinterpret_cast<const float4*>(cb + (size_t)row * D)[lane];
  double s = (double)v.x * v.x + (double)v.y * v.y +
             (double)v.z * v.z + (double)v.w * v.w;
#pragma unroll
  for (int o = 32; o > 0; o >>= 1) s += __shfl_down(s, o, 64);
  if (lane == 0) se[row] = (float)s;
}

// ---------------- kernel 1b: token squared norms (f64 -> f32) -------------
__global__ __launch_bounds__(256) void xx_kernel(const float* __restrict__ x,
                                                 float* __restrict__ sx) {
  const int row = blockIdx.x * 4 + (threadIdx.x >> 6);
  const int lane = threadIdx.x & 63;
  const float4 v = reinterpret_cast<const float4*>(x + (size_t)row * D)[lane];
  double s = (double)v.x * v.x + (double)v.y * v.y +
             (double)v.z * v.z + (double)v.w * v.w;
#pragma unroll
  for (int o = 32; o > 0; o >>= 1) s += __shfl_down(s, o, 64);
  if (lane == 0) sx[row] = (float)s;
}

// ---------------- kernel 1c: pack codebook e_hi -> LDS-image bf16 tiles ---
// tile (bn = c>>7, kt = 0..3) : [row = c&127][64 k-elems], ushort idx within
// tile = row*64 + (koff ^ ((row&7)<<3))  (XOR swizzle baked in; the screen
// kernel stages tiles verbatim via global_load_lds and reads with same XOR).
__global__ __launch_bounds__(256) void pack_e_kernel(const float* __restrict__ cb,
                                                     unsigned short* __restrict__ bpack) {
  const int gid = blockIdx.x * 256 + threadIdx.x;  // 16384 = 4096 codes x 4 kt
  const int c = gid >> 2;
  const int kt = gid & 3;
  const int row = c & 127;
  const int swz = (row & 7) << 3;
  unsigned short* dst = bpack + ((size_t)((c >> 7) * 4 + kt)) * 8192 + row * 64;
  const float* src = cb + (size_t)c * D + kt * 64;
#pragma unroll
  for (int j = 0; j < 8; ++j) {
    ushort8 o;
#pragma unroll
    for (int e = 0; e < 8; ++e) o[e] = f2bf(src[j * 8 + e]);
    *reinterpret_cast<ushort8*>(dst + ((j * 8) ^ swz)) = o;
  }
}

// ---------------- kernel 2: MFMA screening -> per-token candidate lists ---
// Block: 128 tokens, 4 waves; wave w owns tokens w*32..w*32+31 x all 128
// codes of each code-tile. A = (x_hi + x_lo) bf16 pairs in VGPRs (loaded
// once); B = e_hi streamed 16KB units via global_load_lds (triple buffer),
// each B-frag feeds hi AND lo MFMA (256 B/MFMA). d~ = se - 2*(xh+xl)?e_hi;
// every code with d~ <= running_min + DELTA goes into the token's list.
// Coverage proof: |d~ - d_true| <= 8sigma(x?e_lo)=4.2e-5 (Gaussian, x?cb) and
// reference-chain order flips need true gap <= 6.2e-5 => DELTA=1.5e-4 covers.
__global__ __launch_bounds__(256, 2) void screen_kernel(
    const float* __restrict__ x, const unsigned short* __restrict__ bpack,
    const float* __restrict__ se, unsigned int* __restrict__ ccnt_g,
    int* __restrict__ cand_g) {
  __shared__ __attribute__((aligned(16))) unsigned short bbuf[3][8192];  // 48KB
  __shared__ int cand[128][32];                                          // 16KB
  __shared__ unsigned int ccnt[128];

  const int tid = threadIdx.x;
  const int lane = tid & 63;
  const int w = tid >> 6;
  const int l15 = lane & 15;
  const int kg = lane >> 4;  // 0..3 : k-group within fragment
  const int tok0 = blockIdx.x * 128;

  if (tid < 128) ccnt[tid] = 0;

  // stage first two B units while we build A fragments
  {
    const char* s0 = (const char*)bpack + (size_t)w * 4096 + lane * 16;
#pragma unroll
    for (int r = 0; r < 4; ++r) {
      gload_lds16((const float*)(s0 + r * 1024),
                  (float*)((char*)&bbuf[0][0] + w * 4096 + r * 1024));
      gload_lds16((const float*)(s0 + 16384 + r * 1024),
                  (float*)((char*)&bbuf[1][0] + w * 4096 + r * 1024));
    }
  }

  // A fragments: 2 row-groups x 8 ksteps, hi and lo  (128 VGPRs)
  bf16x8 ah[2][8], al[2][8];
#pragma unroll
  for (int gi = 0; gi < 2; ++gi) {
    const int t = tok0 + w * 32 + gi * 16 + l15;
    const float* xp = x + (size_t)t * D;
#pragma unroll
    for (int ks = 0; ks < 8; ++ks) {
      const float4 v0 = *reinterpret_cast<const float4*>(xp + ks * 32 + kg * 8);
      const float4 v1 = *reinterpret_cast<const float4*>(xp + ks * 32 + kg * 8 + 4);
      const float xv[8] = {v0.x, v0.y, v0.z, v0.w, v1.x, v1.y, v1.z, v1.w};
      bf16x8 h, l;
#pragma unroll
      for (int e = 0; e < 8; ++e) {
        const unsigned short hb = f2bf(xv[e]);
        h[e] = (short)hb;
        l[e] = (short)f2bf(xv[e] - bf2f(hb));
      }
      ah[gi][ks] = h;
      al[gi][ks] = l;
    }
  }

  float rm[2][4];
#pragma unroll
  for (int fr = 0; fr < 2; ++fr)
#pragma unroll
    for (int q = 0; q < 4; ++q) rm[fr][q] = 3.4e38f;

  f32x4 acc[2][8];
  __syncthreads();  // first two units resident; ccnt zeroed

  int rb = 0, wb = 2;
  for (int u = 0; u < 128; ++u) {  // unit = (ct = u>>2, kt = u&3)
    if (u + 2 < 128) {
      const char* s0 = (const char*)bpack + (size_t)(u + 2) * 16384 +
                       w * 4096 + lane * 16;
      char* d0 = (char*)&bbuf[wb][0] + w * 4096;
#pragma unroll
      for (int r = 0; r < 4; ++r)
        gload_lds16((const float*)(s0 + r * 1024), (float*)(d0 + r * 1024));
    }
    const int kt = u & 3;
    if (kt == 0) {
#pragma unroll
      for (int fr = 0; fr < 2; ++fr)
#pragma unroll
        for (int fc = 0; fc < 8; ++fc) acc[fr][fc] = (f32x4){0.f, 0.f, 0.f, 0.f};
    }
    const unsigned short* bb = &bbuf[rb][0];
#pragma unroll
    for (int kh = 0; kh < 2; ++kh) {
      bf16x8 bfrag[8];
#pragma unroll
      for (int fc = 0; fc < 8; ++fc) {
        const int row = fc * 16 + l15;
        const int off = row * 64 + ((kh * 32 + kg * 8) ^ ((row & 7) << 3));
        bfrag[fc] = *reinterpret_cast<const bf16x8*>(bb + off);
      }
      const int ks = kt * 2 + kh;
#pragma unroll
      for (int fr = 0; fr < 2; ++fr)
#pragma unroll
        for (int fc = 0; fc < 8; ++fc) {
          acc[fr][fc] = __builtin_amdgcn_mfma_f32_16x16x32_bf16(
              ah[fr][ks], bfrag[fc], acc[fr][fc], 0, 0, 0);
          acc[fr][fc] = __builtin_amdgcn_mfma_f32_16x16x32_bf16(
              al[fr][ks], bfrag[fc], acc[fr][fc], 0, 0, 0);
        }
    }
    if (kt == 3) {  // ct finished: update running mins, insert candidates
      const int ct = u >> 2;
      float sef[8];
#pragma unroll
      for (int fc = 0; fc < 8; ++fc) sef[fc] = se[ct * 128 + fc * 16 + l15];
#pragma unroll
      for (int fr = 0; fr < 2; ++fr)
#pragma unroll
        for (int q = 0; q < 4; ++q) {
          float m = fmaf(-2.0f, acc[fr][0][q], sef[0]);
#pragma unroll
          for (int fc = 1; fc < 8; ++fc)
            m = fminf(m, fmaf(-2.0f, acc[fr][fc][q], sef[fc]));
          m = fminf(m, __shfl_xor(m, 1, 64));
          m = fminf(m, __shfl_xor(m, 2, 64));
          m = fminf(m, __shfl_xor(m, 4, 64));
          m = fminf(m, __shfl_xor(m, 8, 64));
          rm[fr][q] = fminf(rm[fr][q], m);
          const float thr = rm[fr][q] + DELTA;
          const int tl = w * 32 + fr * 16 + kg * 4 + q;
#pragma unroll
          for (int fc = 0; fc < 8; ++fc) {
            const float s = fmaf(-2.0f, acc[fr][fc][q], sef[fc]);
            if (s <= thr) {
              const unsigned p = atomicAdd(&ccnt[tl], 1u);
              if (p < 32) cand[tl][p] = ct * 128 + fc * 16 + l15;
            }
          }
        }
    }
    __syncthreads();
    rb = (rb == 2) ? 0 : rb + 1;
    wb = (wb == 2) ? 0 : wb + 1;
  }

  if (tid < 128) ccnt_g[tok0 + tid] = ccnt[tid];
  for (int j = tid; j < 128 * 32; j += 256)
    cand_g[(size_t)tok0 * 32 + j] = cand[j >> 5][j & 31];
}

// ---------------- kernel 3: exact-chain rescore over candidate lists ------
// One thread per token. Replicates the (round-3-proven) reference f32
// semantics bit-for-bat on <=32 candidates: sequential fmaf chain d=0..255,
// dist = fl(fl(sx+se)-2*dot), lex-min (dist, idx).
__global__ __launch_bounds__(256) void rescore_kernel(
    const float* __restrict__ x, const float* __restrict__ cb,
    const float* __restrict__ se, const float* __restrict__ sx,
    const unsigned int* __restrict__ ccnt_g, const int* __restrict__ cand_g,
    int* __restrict__ idx_i, float* __restrict__ idxf_out,
    unsigned int* __restrict__ ovf_count, int* __restrict__ ovf_list) {
  const int t = blockIdx.x * 256 + threadIdx.x;
  const unsigned n = ccnt_g[t];
  if (n > 32) {  // list overflowed: defer to full-scan fallback
    const unsigned p = atomicAdd(ovf_count, 1u);
    ovf_list[p] = t;
    return;
  }
  const float sxv = sx[t];
  const float4* xp = reinterpret_cast<const float4*>(x + (size_t)t * D);
  float bq = 3.4e38f;
  int bc = 0x7fffffff;
  for (unsigned k = 0; k < n; ++k) {
    const int c = cand_g[(size_t)t * 32 + k];
    const float4* cp = reinterpret_cast<const float4*>(cb + (size_t)c * D);
    float acc = 0.0f;
#pragma unroll 8
    for (int d4 = 0; d4 < 64; ++d4) {
      const float4 xv = xp[d4];
      const float4 ev = cp[d4];
      acc = fmaf(xv.x, ev.x, acc);
      acc = fmaf(xv.y, ev.y, acc);
      acc = fmaf(xv.z, ev.z, acc);
      acc = fmaf(xv.w, ev.w, acc);
    }
    const float r = sxv + se[c];
    const float q = r - 2.0f * acc;
    if (q < bq || (q == bq && c < bc)) { bq = q; bc = c; }
  }
  idx_i[t] = bc;
  idxf_out[t] = (float)bc;
}

// ---------------- kernel 3b: full-scan fallback for overflowed tokens -----
__global__ __launch_bounds__(256) void ovf_kernel(
    const float* __restrict__ x, const float* __restrict__ cb,
    const float* __restrict__ se, const float* __restrict__ sx,
    const unsigned int* __restrict__ ovf_count, const int* __restrict__ ovf_list,
    int* __restrict__ idx_i, float* __restrict__ idxf_out) {
  __shared__ float bvv[256];
  __shared__ int bii[256];
  const int tid = threadIdx.x;
  const unsigned cnt = *ovf_count;
  for (unsigned i = blockIdx.x; i < cnt; i += gridDim.x) {
    const int t = ovf_list[i];
    const float sxv = sx[t];
    const float4* xp = reinterpret_cast<const float4*>(x + (size_t)t * D);
    float bq = 3.4e38f;
    int bc = 0x7fffffff;
    for (int c = tid; c < KCODES; c += 256) {
      const float4* cp = reinterpret_cast<const float4*>(cb + (size_t)c * D);
      float acc = 0.0f;
#pragma unroll 8
      for (int d4 = 0; d4 < 64; ++d4) {
        const float4 xv = xp[d4];
        const float4 ev = cp[d4];
        acc = fmaf(xv.x, ev.x, acc);
        acc = fmaf(xv.y, ev.y, acc);
        acc = fmaf(xv.z, ev.z, acc);
        acc = fmaf(xv.w, ev.w, acc);
      }
      const float r = sxv + se[c];
      const float q = r - 2.0f * acc;
      if (q < bq || (q == bq && c < bc)) { bq = q; bc = c; }
    }
    bvv[tid] = bq;
    bii[tid] = bc;
    __syncthreads();
    for (int o = 128; o > 0; o >>= 1) {
      if (tid < o) {
        const float v2 = bvv[tid + o];
        const int c2 = bii[tid + o];
        if (v2 < bvv[tid] || (v2 == bvv[tid] && c2 < bii[tid])) {
          bvv[tid] = v2;
          bii[tid] = c2;
        }
      }
      __syncthreads();
    }
    if (tid == 0) {
      idx_i[t] = bii[0];
      idxf_out[t] = (float)bii[0];
    }
    __syncthreads();
  }
}

// ---------------- fallback argmin (tiny-ws path; round-4 kernel) ----------
__global__ __launch_bounds__(256) void argmin_fb_kernel(const float* __restrict__ x,
                                                        const float* __restrict__ cb,
                                                        const float* __restrict__ se,
                                                        const float* __restrict__ sx,
                                                        int* __restrict__ idx_out,
                                                        float* __restrict__ idxf_out) {
  __shared__ __attribute__((aligned(16))) float xs[64 * 128];
  __shared__ __attribute__((aligned(16))) float es[64 * 128];
  const int tid = threadIdx.x;
  const int lane = tid & 63;
  const int w = tid >> 6;
  const int wt = w & 1;
  const int wc = w >> 1;
  const int tgl = lane & 7;
  const int cgl = lane >> 3;
  const int t0 = wt * 64 + tgl * 8;
  const int c0 = wc * 64 + cgl * 8;
  const int tok0 = blockIdx.x * 128;
  float sxf[8];
#pragma unroll
  for (int i = 0; i < 8; ++i) sxf[i] = sx[tok0 + t0 + i];
  float bv[8];
  int bi[8];
#pragma unroll
  for (int i = 0; i < 8; ++i) { bv[i] = 3.4e38f; bi[i] = 0; }
  for (int ct = 0; ct < KCODES / 128; ++ct) {
    float acc[8][8] = {};
    for (int kt = 0; kt < 4; ++kt) {
      __syncthreads();
      {
        const float* xsrc = x + (size_t)tok0 * D + kt * 64;
        const float* esrc = cb + (size_t)(ct * 128) * D + kt * 64;
#pragma unroll
        for (int p = 0; p < 8; ++p) {
          const int idx = p * 256 + tid;
          const int t = idx >> 4;
          const int c = idx & 15;
          const int colp = (t + 8 * (c >> 1)) & 127;
          const float4 xv = *reinterpret_cast<const float4*>(xsrc + (size_t)t * D + c * 4);
          float* xd = &xs[(c * 4) * 128 + colp];
          xd[0] = xv.x; xd[128] = xv.y; xd[256] = xv.z; xd[384] = xv.w;
          const float4 ev = *reinterpret_cast<const float4*>(esrc + (size_t)t * D + c * 4);
          float* ed = &es[(c * 4) * 128 + colp];
          ed[0] = ev.x; ed[128] = ev.y; ed[256] = ev.z; ed[384] = ev.w;
        }
      }
      __syncthreads();
      for (int kp = 0; kp < 8; ++kp) {
        const float* xb = &xs[(kp * 8) * 128 + ((t0 + 8 * kp) & 127)];
        const float* eb = &es[(kp * 8) * 128 + ((c0 + 8 * kp) & 127)];
#pragma unroll
        for (int k2 = 0; k2 < 8; ++k2) {
          const float4 xv0 = *reinterpret_cast<const float4*>(xb + k2 * 128);
          const float4 xv1 = *reinterpret_cast<const float4*>(xb + k2 * 128 + 4);
          const float4 ev0 = *reinterpret_cast<const float4*>(eb + k2 * 128);
          const float4 ev1 = *reinterpret_cast<const float4*>(eb + k2 * 128 + 4);
          const float xa[8] = {xv0.x, xv0.y, xv0.z, xv0.w, xv1.x, xv1.y, xv1.z, xv1.w};
          const float ea[8] = {ev0.x, ev0.y, ev0.z, ev0.w, ev1.x, ev1.y, ev1.z, ev1.w};
#pragma unroll
          for (int i = 0; i < 8; ++i)
#pragma unroll
            for (int j = 0; j < 8; ++j) acc[i][j] = fmaf(xa[i], ea[j], acc[i][j]);
        }
      }
    }
#pragma unroll
    for (int j = 0; j < 8; ++j) {
      const int cidx = ct * 128 + c0 + j;
      const float sef = se[cidx];
#pragma unroll
      for (int i = 0; i < 8; ++i) {
        const float r = sxf[i] + sef;
        const float s = r - 2.0f * acc[i][j];
        if (s < bv[i]) { bv[i] = s; bi[i] = cidx; }
      }
    }
  }
  __syncthreads();
  float* red_val = xs;
  int* red_idx = reinterpret_cast<int*>(xs + 128 * 17);
  const int g = wc * 8 + cgl;
#pragma unroll
  for (int i = 0; i < 8; ++i) {
    red_val[(t0 + i) * 17 + g] = bv[i];
    red_idx[(t0 + i) * 17 + g] = bi[i];
  }
  __syncthreads();
  if (tid < 128) {
    float v = red_val[tid * 17 + 0];
    int ix = red_idx[tid * 17 + 0];
#pragma unroll
    for (int gg = 1; gg < 16; ++gg) {
      const float vv = red_val[tid * 17 + gg];
      const int ii = red_idx[tid * 17 + gg];
      if (vv < v || (vv == v && ii < ix)) { v = vv; ix = ii; }
    }
    idx_out[tok0 + tid] = ix;
    idxf_out[tok0 + tid] = (float)ix;
  }
}

// ---------------- kernel 4: gather, q_st, loss partials, histogram --------
__global__ __launch_bounds__(256) void finalize_kernel(const float* __restrict__ x,
                                                       const float* __restrict__ cb,
                                                       const int* __restrict__ idx,
                                                       float* __restrict__ q_out,
                                                       unsigned int* __restrict__ counts,
                                                       double* __restrict__ partials) {
  __shared__ double tok_s[16];
  const int tid = threadIdx.x;
  const int lt = tid >> 4;
  const int ld = tid & 15;
  const int t = blockIdx.x * 16 + lt;
  const int id = idx[t];
  const float* xp = x + (size_t)t * D + ld * 16;
  const float* ep = cb + (size_t)id * D + ld * 16;
  float* qp = q_out + (size_t)t * D + ld * 16;
  float s = 0.0f;
#pragma unroll
  for (int c = 0; c < 4; ++c) {
    const float4 xv = reinterpret_cast<const float4*>(xp)[c];
    const float4 ev = reinterpret_cast<const float4*>(ep)[c];
    const float d0 = ev.x - xv.x, d1 = ev.y - xv.y;
    const float d2 = ev.z - xv.z, d3 = ev.w - xv.w;
    s = fmaf(d0, d0, s);
    s = fmaf(d1, d1, s);
    s = fmaf(d2, d2, s);
    s = fmaf(d3, d3, s);
    float4 qv;  // q_st = x + (q - x), as the reference computes it
    qv.x = xv.x + d0;
    qv.y = xv.y + d1;
    qv.z = xv.z + d2;
    qv.w = xv.w + d3;
    reinterpret_cast<float4*>(qp)[c] = qv;
  }
#pragma unroll
  for (int o = 8; o > 0; o >>= 1) s += __shfl_down(s, o, 16);
  if (ld == 0) {
    atomicAdd(&counts[id], 1u);
    tok_s[lt] = (double)s;
  }
  __syncthreads();
  if (tid == 0) {
    double bs = 0.0;
    for (int i = 0; i < 16; ++i) bs += tok_s[i];
    partials[blockIdx.x] = bs;
  }
}

// ---------------- kernel 5: scalar reductions ----------------
__global__ __launch_bounds__(256) void final_kernel(const unsigned int* __restrict__ counts,
                                                    const double* __restrict__ partials,
                                                    float* __restrict__ loss_out,
                                                    float* __restrict__ perp_out) {
  __shared__ double sh[256];
  const int tid = threadIdx.x;
  double ls = 0.0;
  for (int i = tid; i < NTOK / 16; i += 256) ls += partials[i];
  sh[tid] = ls;
  __syncthreads();
#pragma unroll
  for (int o = 128; o > 0; o >>= 1) {
    if (tid < o) sh[tid] += sh[tid + o];
    __syncthreads();
  }
  if (tid == 0) {
    *loss_out = (float)(sh[0] * (1.25 / (256.0 * 65536.0)));
  }
  __syncthreads();
  double hs = 0.0;
  for (int i = tid; i < KCODES; i += 256) {
    const float p = (float)counts[i] / 65536.0f;
    hs += (double)(p * logf(p + 1e-10f));
  }
  sh[tid] = hs;
  __syncthreads();
#pragma unroll
  for (int o = 128; o > 0; o >>= 1) {
    if (tid < o) sh[tid] += sh[tid + o];
    __syncthreads();
  }
  if (tid == 0) *perp_out = expf((float)(-sh[0]));
}

extern "C" void kernel_launch(void* const* d_in, const int* in_sizes, int n_in,
                              void* d_out, int out_size, void* d_ws, size_t ws_size,
                              hipStream_t stream) {
  (void)in_sizes; (void)n_in; (void)out_size;
  const float* x = (const float*)d_in[0];
  const float* cb = (const float*)d_in[1];

  float* out = (float*)d_out;
  float* q_out = out;                                  // [0, 16777216)
  float* loss_out = out + (size_t)Q_ELEMS;             // [16777216]
  float* perp_out = out + (size_t)Q_ELEMS + 1;         // [16777217]
  float* idxf_out = out + (size_t)Q_ELEMS + 2;         // [16777218, +65536)

  // ws layout (bytes):
  //   se f32[4096]        @0
  //   counts u32[4096]    @16K
  //   partials f64[4096]  @32K
  //   idx i32[65536]      @64K
  //   sx f32[65536]       @320K
  //   ovf_count u32       @576K
  //   ovf_list i32[65536] @580K
  //   ccnt_g u32[65536]   @1M
  //   cand_g i32[65536*32]@2M   (8MB)
  //   bpack bf16[4096*256]@10M  (2MB)   -> total 12MB
  char* ws = (char*)d_ws;
  float* se = (float*)(ws + 0);
  unsigned int* counts = (unsigned int*)(ws + (16 << 10));
  double* partials = (double*)(ws + (32 << 10));
  int* idx_i = (int*)(ws + (64 << 10));
  float* sx = (float*)(ws + (320 << 10));
  unsigned int* ovf_count = (unsigned int*)(ws + (576 << 10));
  int* ovf_list = (int*)(ws + (580 << 10));
  unsigned int* ccnt_g = (unsigned int*)(ws + (1 << 20));
  int* cand_g = (int*)(ws + (2 << 20));
  unsigned short* bpack = (unsigned short*)(ws + (10 << 20));

  hipMemsetAsync(counts, 0, KCODES * sizeof(unsigned int), stream);
  hipMemsetAsync(ovf_count, 0, sizeof(unsigned int), stream);
  ee_kernel<<<KCODES / 4, 256, 0, stream>>>(cb, se);
  xx_kernel<<<NTOK / 4, 256, 0, stream>>>(x, sx);

  if (ws_size >= (size_t)13 * 1024 * 1024) {
    pack_e_kernel<<<64, 256, 0, stream>>>(cb, bpack);
    screen_kernel<<<NTOK / 128, 256, 0, stream>>>(x, bpack, se, ccnt_g, cand_g);
    rescore_kernel<<<NTOK / 256, 256, 0, stream>>>(x, cb, se, sx, ccnt_g, cand_g,
                                                   idx_i, idxf_out, ovf_count, ovf_list);
    ovf_kernel<<<64, 256, 0, stream>>>(x, cb, se, sx, ovf_count, ovf_list,
                                       idx_i, idxf_out);
  } else {
    argmin_fb_kernel<<<NTOK / 128, 256, 0, stream>>>(x, cb, se, sx, idx_i, idxf_out);
  }
  finalize_kernel<<<NTOK / 16, 256, 0, stream>>>(x, cb, idx_i, q_out, counts, partials);
  final_kernel<<<1, 256, 0, stream>>>(counts, partials, loss_out, perp_out);
}